// Round 3
// baseline (1248.527 us; speedup 1.0000x reference)
//
#include <hip/hip_runtime.h>
#include <math.h>

#define DEVINL __device__ __forceinline__

// ---- wave-parallel decoupled lookback (call from threads 0..63 only).
// look[] entries: (flag<<40) | value; flag 0=empty, 1=aggregate, 2=inclusive.
// Returns exclusive base (valid on lane 0 only).
DEVINL unsigned lookback_base(unsigned long long* look, int id, unsigned total, int lane) {
  if (id == 0) {
    if (lane == 0)
      __hip_atomic_store(&look[0], (2ull << 40) | (unsigned long long)total,
                         __ATOMIC_RELEASE, __HIP_MEMORY_SCOPE_AGENT);
    return 0;
  }
  if (lane == 0)
    __hip_atomic_store(&look[id], (1ull << 40) | (unsigned long long)total,
                       __ATOMIC_RELEASE, __HIP_MEMORY_SCOPE_AGENT);
  unsigned base = 0;
  int p = id - 1;
  for (;;) {
    int idx = p - lane;  // lane 0 reads nearest predecessor
    unsigned long long v = 0;
    if (idx >= 0) {
      do {
        v = __hip_atomic_load(&look[idx], __ATOMIC_ACQUIRE, __HIP_MEMORY_SCOPE_AGENT);
        if ((v >> 40) == 0) __builtin_amdgcn_s_sleep(1);
      } while ((v >> 40) == 0);
    }
    unsigned long long m2 = __ballot((idx >= 0) && ((v >> 40) == 2));
    int stop = m2 ? (__ffsll(m2) - 1) : 64;  // lowest lane with inclusive = nearest
    unsigned c = ((idx >= 0) && (lane <= stop)) ? (unsigned)(v & 0xFFFFFFFFull) : 0u;
    for (int off = 32; off > 0; off >>= 1) c += __shfl_down(c, off, 64);
    if (lane == 0) base += c;
    if (m2) break;
    p -= 64;  // block 0 always ends flag=2, so termination is guaranteed
  }
  if (lane == 0)
    __hip_atomic_store(&look[id], (2ull << 40) | (unsigned long long)(base + total),
                       __ATOMIC_RELEASE, __HIP_MEMORY_SCOPE_AGENT);
  return base;
}

// ---------------- scores (fp64 accumulate) + fused hi16 histogram ----------------
__global__ __launch_bounds__(256) void scores_kernel(
    const float* __restrict__ x, const float* __restrict__ w,
    const float* __restrict__ bptr, int N, int F,
    unsigned* __restrict__ scores, unsigned* __restrict__ hist0) {
  int node = blockIdx.x * 4 + (threadIdx.x >> 6);
  int lane = threadIdx.x & 63;
  if (node >= N) return;
  const float2* xr = (const float2*)(x + (size_t)node * F);
  const float2* w2 = (const float2*)w;
  double acc = 0.0;
  for (int f = lane; f < F / 2; f += 64) {
    float2 xv = xr[f], wv = w2[f];
    acc += (double)xv.x * (double)wv.x + (double)xv.y * (double)wv.y;
  }
  for (int off = 32; off > 0; off >>= 1) acc += __shfl_down(acc, off, 64);
  if (lane == 0) {
    double z = acc + (double)bptr[0];
    unsigned bits = __float_as_uint((float)(1.0 / (1.0 + exp(-z))));
    scores[node] = bits;  // sigmoid>0: bits are order-monotone
    atomicAdd(&hist0[bits >> 16], 1u);
  }
}

// ---------------- pass-1 histogram: lo16 within selected hi16 bucket ----------------
__global__ __launch_bounds__(256) void hist1_kernel(
    const unsigned* __restrict__ scores, int N, unsigned* __restrict__ hist,
    const unsigned* __restrict__ sel) {
  int i = blockIdx.x * 256 + threadIdx.x;
  if (i >= N) return;
  unsigned bits = scores[i];
  if ((bits >> 16) == sel[0]) atomicAdd(&hist[bits & 0xFFFFu], 1u);
}

// find bucket containing rank q (ascending); outB = bucket, outRem = rank within bucket
__global__ __launch_bounds__(256) void select_kernel(
    const unsigned* __restrict__ hist, const unsigned* __restrict__ qptr, unsigned qconst,
    unsigned* __restrict__ outB, unsigned* __restrict__ outRem) {
  __shared__ unsigned tot[256];
  __shared__ unsigned bins[256];
  __shared__ unsigned sChunk, sRem;
  int t = threadIdx.x;
  unsigned q = qptr ? *qptr : qconst;
  const unsigned* hp = hist + t * 256;
  unsigned s = 0;
  for (int j = 0; j < 256; j++) s += hp[j];
  tot[t] = s;
  __syncthreads();
  if (t == 0) {
    unsigned cum = 0; int c = 0;
    for (; c < 256; c++) { if (q < cum + tot[c]) break; cum += tot[c]; }
    sChunk = (unsigned)c; sRem = q - cum;
  }
  __syncthreads();
  bins[t] = hist[sChunk * 256 + t];
  __syncthreads();
  if (t == 0) {
    unsigned cum = 0; unsigned q2 = sRem; int bi = 0;
    for (; bi < 256; bi++) { if (q2 < cum + bins[bi]) break; cum += bins[bi]; }
    *outB = sChunk * 256 + bi;
    *outRem = q2 - cum;
  }
}

// ------- node pass: mask + lookback scan + map/pool_indices + fused new_x copy -------
__global__ __launch_bounds__(256) void node_pass(
    const unsigned* __restrict__ scores, const unsigned* __restrict__ sel,
    const float* __restrict__ x, int N, int F, int n_keep,
    unsigned* __restrict__ ctr, unsigned long long* __restrict__ look,
    int* __restrict__ map, float* __restrict__ out_pool, float* __restrict__ out_x) {
  __shared__ unsigned s_id, s_base;
  __shared__ unsigned wv[4];
  __shared__ int keep_src[256];
  int t = threadIdx.x;
  if (t == 0) s_id = atomicAdd(ctr, 1u);
  __syncthreads();
  int id = (int)s_id;
  int i = id * 256 + t;
  unsigned T = (sel[0] << 16) | sel[2];
  int m = (i < N) && (scores[i] >= T);
  unsigned long long bal = __ballot(m);
  int lane = t & 63, wave = t >> 6;
  if (lane == 0) wv[wave] = (unsigned)__popcll(bal);
  __syncthreads();
  unsigned total = wv[0] + wv[1] + wv[2] + wv[3];
  unsigned pre = (unsigned)__popcll(bal & ((1ull << lane) - 1ull));
  for (int k = 0; k < wave; k++) pre += wv[k];
  if (t < 64) {
    unsigned b = lookback_base(look, id, total, lane);
    if (lane == 0) s_base = b;
  }
  __syncthreads();
  unsigned base = s_base;
  int kc = n_keep - (int)base;                       // kept rows in this block
  kc = kc < 0 ? 0 : (kc > (int)total ? (int)total : kc);
  if (i < N) {
    int rank = -1;
    if (m && base + pre < (unsigned)n_keep) {
      rank = (int)(base + pre);
      out_pool[rank] = (float)i;
      keep_src[pre] = i;                             // kept lanes form prefix [0,kc)
    }
    map[i] = rank;
  }
  __syncthreads();
  // cooperative row copy: F floats = F/4 float4s per row; tpr threads per row
  int tpr = F / 4;                                   // 32 for F=128
  int rpi = 256 / tpr;                               // 8 rows per iteration
  int jrow = t / tpr, c = t % tpr;
  for (int j0 = 0; j0 < kc; j0 += rpi) {
    int j = j0 + jrow;
    if (j < kc) {
      const float4* s = (const float4*)(x + (size_t)keep_src[j] * F);
      float4* d = (float4*)(out_x + (size_t)(base + (unsigned)j) * F);
      d[c] = s[c];
    }
  }
}

// --- edge pass: mask + pool_edges + lookback scan + compacted idx/remap/attr copy ---
__global__ __launch_bounds__(256) void edge_pass(
    const int* __restrict__ ei, const int* __restrict__ map,
    const float* __restrict__ attr, int E, int Ek, int Fe,
    unsigned* __restrict__ ctr, unsigned long long* __restrict__ look,
    float* __restrict__ out, size_t o_ei, size_t o_eio, size_t o_attr, size_t o_pe) {
  __shared__ unsigned s_id, s_base;
  __shared__ unsigned wv[4];
  __shared__ int keepE[256];
  __shared__ float kA[256], kB[256], kMA[256], kMB[256];
  int t = threadIdx.x;
  if (t == 0) s_id = atomicAdd(ctr, 1u);
  __syncthreads();
  int id = (int)s_id;
  int e = id * 256 + t;
  int m = 0, a = 0, b = 0, ma = -1, mb = -1;
  if (e < E) {
    a = ei[e]; b = ei[E + e];
    ma = map[a]; mb = map[b];
    m = (ma >= 0) && (mb >= 0);
    out[o_pe + e] = m ? 1.0f : 0.0f;
  }
  unsigned long long bal = __ballot(m);
  int lane = t & 63, wave = t >> 6;
  if (lane == 0) wv[wave] = (unsigned)__popcll(bal);
  __syncthreads();
  unsigned total = wv[0] + wv[1] + wv[2] + wv[3];
  unsigned pre = (unsigned)__popcll(bal & ((1ull << lane) - 1ull));
  for (int k = 0; k < wave; k++) pre += wv[k];
  if (m) {
    keepE[pre] = e;
    kA[pre] = (float)a; kB[pre] = (float)b;
    kMA[pre] = (float)ma; kMB[pre] = (float)mb;
  }
  if (t < 64) {
    unsigned bs = lookback_base(look, id, total, lane);
    if (lane == 0) s_base = bs;
  }
  __syncthreads();
  unsigned base = s_base;
  // coalesced compacted index writes (4 streams)
  for (unsigned j = t; j < total; j += 256) {
    unsigned p = base + j;
    out[o_ei + p]               = kA[j];
    out[o_ei + (size_t)Ek + p]  = kB[j];
    out[o_eio + p]              = kMA[j];
    out[o_eio + (size_t)Ek + p] = kMB[j];
  }
  // cooperative attr row copy: Fe floats = Fe/4 float4s; tpr threads per row
  int tpr = Fe / 4;                                  // 8 for Fe=32
  int rpi = 256 / tpr;                               // 32 rows per iteration
  int jrow = t / tpr, c = t % tpr;
  for (int j0 = 0; j0 < (int)total; j0 += rpi) {
    int j = j0 + jrow;
    if (j < (int)total) {
      const float4* s = (const float4*)(attr + (size_t)keepE[j] * Fe);
      float4* d = (float4*)(out + o_attr + (size_t)(base + (unsigned)j) * Fe);
      d[c] = s[c];
    }
  }
}

extern "C" void kernel_launch(void* const* d_in, const int* in_sizes, int n_in,
                              void* d_out, int out_size, void* d_ws, size_t ws_size,
                              hipStream_t stream) {
  const int F  = in_sizes[2];        // 128
  const int E  = in_sizes[4] / 2;    // 1,600,000
  const int N  = in_sizes[0] / F;    // 100,000
  const int Fe = in_sizes[1] / E;    // 32
  const int n_keep = N / 2;          // int(N * K_FRAC), K_FRAC = 0.5
  const unsigned q = (unsigned)(N - n_keep - 1);  // 0-based ascending order stat
  const int Ek = (int)(((long long)out_size - (long long)n_keep * F - n_keep - E) / (4 + Fe));

  const float* x    = (const float*)d_in[0];
  const float* attr = (const float*)d_in[1];
  const float* w    = (const float*)d_in[2];
  const float* b    = (const float*)d_in[3];
  const int*   ei   = (const int*)d_in[4];
  float*       out  = (float*)d_out;

  const size_t o_ei   = (size_t)n_keep * F;
  const size_t o_eio  = o_ei + 2 * (size_t)Ek;
  const size_t o_attr = o_eio + 2 * (size_t)Ek;
  const size_t o_pool = o_attr + (size_t)Ek * Fe;
  const size_t o_pe   = o_pool + (size_t)n_keep;

  const int nb_n = (N + 255) / 256;
  const int nb_e = (E + 255) / 256;

  // workspace carve; everything up to zero_bytes is zeroed each launch
  char* wsb = (char*)d_ws;
  size_t off = 0;
  auto carve = [&](size_t bytes) -> void* {
    void* p = wsb + off;
    off = (off + bytes + 255) & ~(size_t)255;
    return p;
  };
  unsigned* hist0 = (unsigned*)carve((size_t)65536 * 4);
  unsigned* hist1 = (unsigned*)carve((size_t)65536 * 4);
  unsigned* sel   = (unsigned*)carve(64);
  unsigned* ctrs  = (unsigned*)carve(64);             // [0]=node, [8]=edge
  unsigned long long* lookN = (unsigned long long*)carve((size_t)nb_n * 8);
  unsigned long long* lookE = (unsigned long long*)carve((size_t)nb_e * 8);
  const size_t zero_bytes = off;
  unsigned* scores = (unsigned*)carve((size_t)N * 4);
  int* map         = (int*)carve((size_t)N * 4);

  hipMemsetAsync(wsb, 0, zero_bytes, stream);
  scores_kernel<<<(N + 3) / 4, 256, 0, stream>>>(x, w, b, N, F, scores, hist0);
  select_kernel<<<1, 256, 0, stream>>>(hist0, nullptr, q, sel + 0, sel + 1);
  hist1_kernel<<<nb_n, 256, 0, stream>>>(scores, N, hist1, sel);
  select_kernel<<<1, 256, 0, stream>>>(hist1, sel + 1, 0u, sel + 2, sel + 3);
  node_pass<<<nb_n, 256, 0, stream>>>(scores, sel, x, N, F, n_keep,
                                      ctrs + 0, lookN, map, out + o_pool, out);
  edge_pass<<<nb_e, 256, 0, stream>>>(ei, map, attr, E, Ek, Fe,
                                      ctrs + 8, lookE, out, o_ei, o_eio, o_attr, o_pe);
}

// Round 4
// 578.071 us; speedup vs baseline: 2.1598x; 2.1598x over previous
//
#include <hip/hip_runtime.h>
#include <math.h>

#define DEVINL __device__ __forceinline__

// ---- wave-parallel decoupled lookback (call from threads 0..63 only).
// look[] entries: (flag<<40) | value; flag 0=empty, 1=aggregate, 2=inclusive.
// Payload travels in the SAME atomic word as the flag => RELAXED suffices
// (round-3 ACQUIRE polls emitted an L1-invalidate per spin = 763us disaster).
// Returns exclusive base (valid on lane 0 only).
DEVINL unsigned lookback_base(unsigned long long* look, int id, unsigned total, int lane) {
  if (id == 0) {
    if (lane == 0)
      __hip_atomic_store(&look[0], (2ull << 40) | (unsigned long long)total,
                         __ATOMIC_RELAXED, __HIP_MEMORY_SCOPE_AGENT);
    return 0;
  }
  if (lane == 0)
    __hip_atomic_store(&look[id], (1ull << 40) | (unsigned long long)total,
                       __ATOMIC_RELAXED, __HIP_MEMORY_SCOPE_AGENT);
  unsigned base = 0;
  int p = id - 1;
  for (;;) {
    int idx = p - lane;  // lane 0 reads nearest predecessor
    unsigned long long v = 0;
    if (idx >= 0) {
      do {
        v = __hip_atomic_load(&look[idx], __ATOMIC_RELAXED, __HIP_MEMORY_SCOPE_AGENT);
        if ((v >> 40) == 0) __builtin_amdgcn_s_sleep(1);
      } while ((v >> 40) == 0);
    }
    unsigned long long m2 = __ballot((idx >= 0) && ((v >> 40) == 2));
    int stop = m2 ? (__ffsll(m2) - 1) : 64;  // lowest lane with inclusive = nearest
    unsigned c = ((idx >= 0) && (lane <= stop)) ? (unsigned)(v & 0xFFFFFFFFull) : 0u;
    for (int off = 32; off > 0; off >>= 1) c += __shfl_down(c, off, 64);
    if (lane == 0) base += c;
    if (m2) break;
    p -= 64;  // block 0 always ends flag=2, so termination is guaranteed
  }
  if (lane == 0)
    __hip_atomic_store(&look[id], (2ull << 40) | (unsigned long long)(base + total),
                       __ATOMIC_RELAXED, __HIP_MEMORY_SCOPE_AGENT);
  return base;
}

// ---------------- scores (fp64 accumulate) + fused hi16 histogram ----------------
__global__ __launch_bounds__(256) void scores_kernel(
    const float* __restrict__ x, const float* __restrict__ w,
    const float* __restrict__ bptr, int N, int F,
    unsigned* __restrict__ scores, unsigned* __restrict__ hist0) {
  int node = blockIdx.x * 4 + (threadIdx.x >> 6);
  int lane = threadIdx.x & 63;
  if (node >= N) return;
  const float2* xr = (const float2*)(x + (size_t)node * F);
  const float2* w2 = (const float2*)w;
  double acc = 0.0;
  for (int f = lane; f < F / 2; f += 64) {
    float2 xv = xr[f], wv = w2[f];
    acc += (double)xv.x * (double)wv.x + (double)xv.y * (double)wv.y;
  }
  for (int off = 32; off > 0; off >>= 1) acc += __shfl_down(acc, off, 64);
  if (lane == 0) {
    double z = acc + (double)bptr[0];
    unsigned bits = __float_as_uint((float)(1.0 / (1.0 + exp(-z))));
    scores[node] = bits;  // sigmoid>0: bits are order-monotone
    atomicAdd(&hist0[bits >> 16], 1u);
  }
}

// ---------------- pass-1 histogram: lo16 within selected hi16 bucket ----------------
__global__ __launch_bounds__(256) void hist1_kernel(
    const unsigned* __restrict__ scores, int N, unsigned* __restrict__ hist,
    const unsigned* __restrict__ sel) {
  int i = blockIdx.x * 256 + threadIdx.x;
  if (i >= N) return;
  unsigned bits = scores[i];
  if ((bits >> 16) == sel[0]) atomicAdd(&hist[bits & 0xFFFFu], 1u);
}

// find bucket containing rank q (ascending); outB = bucket, outRem = rank within bucket
__global__ __launch_bounds__(256) void select_kernel(
    const unsigned* __restrict__ hist, const unsigned* __restrict__ qptr, unsigned qconst,
    unsigned* __restrict__ outB, unsigned* __restrict__ outRem) {
  __shared__ unsigned tot[256];
  __shared__ unsigned bins[256];
  __shared__ unsigned sChunk, sRem;
  int t = threadIdx.x;
  unsigned q = qptr ? *qptr : qconst;
  const unsigned* hp = hist + t * 256;
  unsigned s = 0;
  for (int j = 0; j < 256; j++) s += hp[j];
  tot[t] = s;
  __syncthreads();
  if (t == 0) {
    unsigned cum = 0; int c = 0;
    for (; c < 256; c++) { if (q < cum + tot[c]) break; cum += tot[c]; }
    sChunk = (unsigned)c; sRem = q - cum;
  }
  __syncthreads();
  bins[t] = hist[sChunk * 256 + t];
  __syncthreads();
  if (t == 0) {
    unsigned cum = 0; unsigned q2 = sRem; int bi = 0;
    for (; bi < 256; bi++) { if (q2 < cum + bins[bi]) break; cum += bins[bi]; }
    *outB = sChunk * 256 + bi;
    *outRem = q2 - cum;
  }
}

// ------- node pass: mask + lookback scan + map/pool_indices + fused new_x copy -------
__global__ __launch_bounds__(256) void node_pass(
    const unsigned* __restrict__ scores, const unsigned* __restrict__ sel,
    const float* __restrict__ x, int N, int F, int n_keep,
    unsigned* __restrict__ ctr, unsigned long long* __restrict__ look,
    int* __restrict__ map, float* __restrict__ out_pool, float* __restrict__ out_x) {
  __shared__ unsigned s_id, s_base;
  __shared__ unsigned wv[4];
  __shared__ int keep_src[256];
  int t = threadIdx.x;
  if (t == 0) s_id = atomicAdd(ctr, 1u);
  __syncthreads();
  int id = (int)s_id;
  int i = id * 256 + t;
  unsigned T = (sel[0] << 16) | sel[2];
  int m = (i < N) && (scores[i] >= T);
  unsigned long long bal = __ballot(m);
  int lane = t & 63, wave = t >> 6;
  if (lane == 0) wv[wave] = (unsigned)__popcll(bal);
  __syncthreads();
  unsigned total = wv[0] + wv[1] + wv[2] + wv[3];
  unsigned pre = (unsigned)__popcll(bal & ((1ull << lane) - 1ull));
  for (int k = 0; k < wave; k++) pre += wv[k];
  if (t < 64) {
    unsigned b = lookback_base(look, id, total, lane);
    if (lane == 0) s_base = b;
  }
  __syncthreads();
  unsigned base = s_base;
  int kc = n_keep - (int)base;                       // kept rows in this block
  kc = kc < 0 ? 0 : (kc > (int)total ? (int)total : kc);
  if (i < N) {
    int rank = -1;
    if (m && base + pre < (unsigned)n_keep) {
      rank = (int)(base + pre);
      out_pool[rank] = (float)i;
      keep_src[pre] = i;                             // kept lanes form prefix [0,kc)
    }
    map[i] = rank;
  }
  __syncthreads();
  // cooperative row copy: F/4 float4s per row
  int tpr = F / 4;                                   // 32 for F=128
  int rpi = 256 / tpr;                               // 8 rows per iteration
  int jrow = t / tpr, col = t % tpr;
  for (int j0 = 0; j0 < kc; j0 += rpi) {
    int j = j0 + jrow;
    if (j < kc) {
      const float4* s4 = (const float4*)(x + (size_t)keep_src[j] * F);
      float4* d4 = (float4*)(out_x + (size_t)(base + (unsigned)j) * F);
      d4[col] = s4[col];
    }
  }
}

// --- edge pass: 2048 edges/block in 8 chunks; ballots in LDS; one lookback ---
#define ENC 8   // chunks per block
__global__ __launch_bounds__(256) void edge_pass(
    const int* __restrict__ ei, const int* __restrict__ map,
    const float* __restrict__ attr, int E, int Ek, int Fe,
    unsigned* __restrict__ ctr, unsigned long long* __restrict__ look,
    float* __restrict__ out, size_t o_ei, size_t o_eio, size_t o_attr, size_t o_pe) {
  __shared__ unsigned s_id, s_base;
  __shared__ unsigned long long ballots[ENC][4];
  __shared__ int keepE[256];
  __shared__ float kA[256], kB[256], kMA[256], kMB[256];
  int t = threadIdx.x, lane = t & 63, wave = t >> 6;
  if (t == 0) s_id = atomicAdd(ctr, 1u);
  __syncthreads();
  int id = (int)s_id;
  int e0 = id * (ENC * 256);
  // ---- phase A: masks + pool_edges + per-chunk ballots
  for (int c = 0; c < ENC; c++) {
    int e = e0 + c * 256 + t;
    int m = 0;
    if (e < E) {
      int a = ei[e], b = ei[E + e];
      m = (map[a] >= 0) && (map[b] >= 0);
      out[o_pe + e] = m ? 1.0f : 0.0f;
    }
    unsigned long long bal = __ballot(m);
    if (lane == 0) ballots[c][wave] = bal;
  }
  __syncthreads();
  unsigned cnt[ENC], cpre[ENC], total = 0;
  for (int c = 0; c < ENC; c++) {
    cpre[c] = total;
    unsigned s = 0;
    for (int k = 0; k < 4; k++) s += (unsigned)__popcll(ballots[c][k]);
    cnt[c] = s; total += s;
  }
  // ---- phase B: one lookback for the whole block
  if (t < 64) {
    unsigned bs = lookback_base(look, id, total, lane);
    if (lane == 0) s_base = bs;
  }
  __syncthreads();
  unsigned base = s_base;
  // ---- phase C: per chunk, stage kept edges in LDS, write coalesced
  for (int c = 0; c < ENC; c++) {
    int e = e0 + c * 256 + t;
    unsigned long long bal = ballots[c][wave];
    int m = (bal >> lane) & 1;
    if (m) {
      unsigned pre = (unsigned)__popcll(bal & ((1ull << lane) - 1ull));
      for (int k = 0; k < wave; k++) pre += (unsigned)__popcll(ballots[c][k]);
      int a = ei[e], b = ei[E + e];                  // L1-warm re-read
      keepE[pre] = e;
      kA[pre] = (float)a;        kB[pre] = (float)b;
      kMA[pre] = (float)map[a];  kMB[pre] = (float)map[b];
    }
    __syncthreads();
    unsigned kcnt = cnt[c], cbase = base + cpre[c];
    for (unsigned j = t; j < kcnt; j += 256) {
      unsigned p = cbase + j;
      out[o_ei + p]               = kA[j];
      out[o_ei + (size_t)Ek + p]  = kB[j];
      out[o_eio + p]              = kMA[j];
      out[o_eio + (size_t)Ek + p] = kMB[j];
    }
    int tpr = Fe / 4;                                // 8 for Fe=32
    int rpi = 256 / tpr;                             // 32 rows per iteration
    int jrow = t / tpr, col = t % tpr;
    for (int j0 = 0; j0 < (int)kcnt; j0 += rpi) {
      int j = j0 + jrow;
      if (j < (int)kcnt) {
        const float4* s4 = (const float4*)(attr + (size_t)keepE[j] * Fe);
        float4* d4 = (float4*)(out + o_attr + (size_t)(cbase + (unsigned)j) * Fe);
        d4[col] = s4[col];
      }
    }
    __syncthreads();
  }
}

extern "C" void kernel_launch(void* const* d_in, const int* in_sizes, int n_in,
                              void* d_out, int out_size, void* d_ws, size_t ws_size,
                              hipStream_t stream) {
  const int F  = in_sizes[2];        // 128
  const int E  = in_sizes[4] / 2;    // 1,600,000
  const int N  = in_sizes[0] / F;    // 100,000
  const int Fe = in_sizes[1] / E;    // 32
  const int n_keep = N / 2;          // int(N * K_FRAC), K_FRAC = 0.5
  const unsigned q = (unsigned)(N - n_keep - 1);  // 0-based ascending order stat
  const int Ek = (int)(((long long)out_size - (long long)n_keep * F - n_keep - E) / (4 + Fe));

  const float* x    = (const float*)d_in[0];
  const float* attr = (const float*)d_in[1];
  const float* w    = (const float*)d_in[2];
  const float* b    = (const float*)d_in[3];
  const int*   ei   = (const int*)d_in[4];
  float*       out  = (float*)d_out;

  const size_t o_ei   = (size_t)n_keep * F;
  const size_t o_eio  = o_ei + 2 * (size_t)Ek;
  const size_t o_attr = o_eio + 2 * (size_t)Ek;
  const size_t o_pool = o_attr + (size_t)Ek * Fe;
  const size_t o_pe   = o_pool + (size_t)n_keep;

  const int nb_n = (N + 255) / 256;                // node blocks (256 nodes each)
  const int nb_e = (E + ENC * 256 - 1) / (ENC * 256);  // edge blocks (2048 edges each)

  // workspace carve; everything up to zero_bytes is zeroed each launch
  char* wsb = (char*)d_ws;
  size_t off = 0;
  auto carve = [&](size_t bytes) -> void* {
    void* p = wsb + off;
    off = (off + bytes + 255) & ~(size_t)255;
    return p;
  };
  unsigned* hist0 = (unsigned*)carve((size_t)65536 * 4);
  unsigned* hist1 = (unsigned*)carve((size_t)65536 * 4);
  unsigned* sel   = (unsigned*)carve(64);
  unsigned* ctrs  = (unsigned*)carve(64);             // [0]=node, [8]=edge
  unsigned long long* lookN = (unsigned long long*)carve((size_t)nb_n * 8);
  unsigned long long* lookE = (unsigned long long*)carve((size_t)nb_e * 8);
  const size_t zero_bytes = off;
  unsigned* scores = (unsigned*)carve((size_t)N * 4);
  int* map         = (int*)carve((size_t)N * 4);

  hipMemsetAsync(wsb, 0, zero_bytes, stream);
  scores_kernel<<<(N + 3) / 4, 256, 0, stream>>>(x, w, b, N, F, scores, hist0);
  select_kernel<<<1, 256, 0, stream>>>(hist0, nullptr, q, sel + 0, sel + 1);
  hist1_kernel<<<(N + 255) / 256, 256, 0, stream>>>(scores, N, hist1, sel);
  select_kernel<<<1, 256, 0, stream>>>(hist1, sel + 1, 0u, sel + 2, sel + 3);
  node_pass<<<nb_n, 256, 0, stream>>>(scores, sel, x, N, F, n_keep,
                                      ctrs + 0, lookN, map, out + o_pool, out);
  edge_pass<<<nb_e, 256, 0, stream>>>(ei, map, attr, E, Ek, Fe,
                                      ctrs + 8, lookE, out, o_ei, o_eio, o_attr, o_pe);
}